// Round 1
// 8579.279 us; speedup vs baseline: 1.2721x; 1.2721x over previous
//
#include <hip/hip_runtime.h>
#include <math.h>

#define TT 2048
#define NSTEP 2053   // 2048 + 4 pipeline fill + 1 head drain

// ---- d_ws layout (bytes) ----
// [0, 262144)   board: u16 [2 parity][32 group][4 batch][512 h]
// [262144, +16K) flags: int [32 group][8 member] stride 16 ints (monotone step cnt)
#define FLAGS_BOFF 262144
#define ZERO_F4    17408     // float4 count covering board+flags

// per-wave private LDS x-buffer: 4 batch rows x XW halves
#define XW  392              // 784B row stride: 196 dwords = 4 mod 32 -> 4-bank row skew
#define XPW (4 * XW)
#define LDS_BYTES 90112      // > 80KB forces 1 block/CU; actual use = 8*XPW*2 = 25088B

typedef _Float16 half2v __attribute__((ext_vector_type(2)));
typedef _Float16 half8v __attribute__((ext_vector_type(8)));

#if defined(__has_builtin)
#if __has_builtin(__builtin_amdgcn_fdot2)
#define HAVE_FDOT2 1
#endif
#endif

__device__ __forceinline__ float fdot2f(half2v a, half2v b, float c) {
#ifdef HAVE_FDOT2
    return __builtin_amdgcn_fdot2(a, b, c, false);
#else
    return c + (float)a.x * (float)b.x + (float)a.y * (float)b.y;
#endif
}
__device__ __forceinline__ half2v h2at(half8v v, int m) {
    half2v r; r.x = v[2 * m]; r.y = v[2 * m + 1]; return r;
}
__device__ __forceinline__ float sigf(float x) { return 1.0f / (1.0f + __expf(-x)); }
__device__ __forceinline__ float tanh_f(float x) {
    float t = __expf(fminf(2.0f * x, 30.0f));
    return (t - 1.0f) / (t + 1.0f);
}

// cross-lane add, xor distance 1/2 via DPP quad_perm (VALU pipe, not LDS)
template<int CTRL, int XM>
__device__ __forceinline__ float xadd(float v) {
#if __has_builtin(__builtin_amdgcn_mov_dpp)
    int t = __builtin_amdgcn_mov_dpp(__builtin_bit_cast(int, v), CTRL, 0xF, 0xF, true);
    return v + __builtin_bit_cast(float, t);
#else
    return v + __shfl_xor(v, XM, 64);
#endif
}
// xor distance 4 via ds_swizzle (1 LDS op, no address VALU)
__device__ __forceinline__ float xadd4(float v) {
#if __has_builtin(__builtin_amdgcn_ds_swizzle)
    int t = __builtin_amdgcn_ds_swizzle(__builtin_bit_cast(int, v), 0x101F);
    return v + __builtin_bit_cast(float, t);
#else
    return v + __shfl_xor(v, 4, 64);
#endif
}

__global__ __launch_bounds__(256)
void prep_zero(float4* ws) {
    int idx = blockIdx.x * 256 + threadIdx.x;
    if (idx < ZERO_F4) ws[idx] = make_float4(0.f, 0.f, 0.f, 0.f);
}

// Stage CNT*16 u64 (= CNT*64 halves) per batch row from board into this wave's
// PRIVATE LDS rows. Board rows are already [batch][h] u16 -> straight copy, no
// transpose. Wave-internal lgkmcnt ordering makes writes visible to this wave's
// later ds_reads without any barrier.
template<int CNT, int KSTART>
__device__ __forceinline__ void stage_x(const unsigned short* __restrict__ bsrc,
                                        _Float16* __restrict__ Xp, int lane)
{
    const int b = lane >> 4, i0 = lane & 15;
    const unsigned long long* src =
        (const unsigned long long*)(bsrc + (size_t)b * 512 + KSTART);
    unsigned long long* dst = (unsigned long long*)(Xp + b * XW);
    unsigned long long v[CNT];
#pragma unroll
    for (int t = 0; t < CNT; ++t)
        v[t] = __hip_atomic_load(src + i0 + t * 16, __ATOMIC_RELAXED,
                                 __HIP_MEMORY_SCOPE_AGENT);
#pragma unroll
    for (int t = 0; t < CNT; ++t)
        dst[i0 + t * 16] = v[t];
}

// One layer slice with register-resident weights. Reduce order (xor 1,2,4)
// identical to the previous shfl butterfly -> bitwise-identical numerics.
template<int RG, int KG, int J, int XLOC, int HBASE, bool ISL1, bool RED8>
__device__ __forceinline__ void layer_v2(
    const half8v* __restrict__ wfrag, const float* __restrict__ brg,
    const float* __restrict__ w1x, float xt,
    const _Float16* __restrict__ Xp,
    unsigned short* __restrict__ brow, float& cpriv, int u, int m)
{
    const int kg = u & (KG - 1);
    const int rg = u / KG;

    float acc[4][4];
#pragma unroll
    for (int i = 0; i < 4; ++i)
#pragma unroll
        for (int j = 0; j < 4; ++j) acc[i][j] = 0.f;

#pragma unroll
    for (int jj = 0; jj < J; ++jj) {
        const int kk = XLOC + kg * 8 + jj * (KG * 8);
        half8v xv[4];
#pragma unroll
        for (int j = 0; j < 4; ++j)
            xv[j] = *(const half8v*)(Xp + j * XW + kk);
#pragma unroll
        for (int i = 0; i < 4; ++i)
#pragma unroll
            for (int j = 0; j < 4; ++j)
#pragma unroll
                for (int mm = 0; mm < 4; ++mm)
                    acc[i][j] = fdot2f(h2at(wfrag[i * J + jj], mm),
                                       h2at(xv[j], mm), acc[i][j]);
    }

#pragma unroll
    for (int i = 0; i < 4; ++i)
#pragma unroll
        for (int j = 0; j < 4; ++j) {
            float a = acc[i][j];
            a = xadd<0xB1, 1>(a);          // quad_perm [1,0,3,2] == xor 1
            a = xadd<0x4E, 2>(a);          // quad_perm [2,3,0,1] == xor 2
            if (RED8) a = xadd4(a);        // ds_swizzle xor 4
            acc[i][j] = a;
        }

    if (kg < 4) {
        const int j = kg;
        float g0 = acc[0][j] + brg[0];
        float g1 = acc[1][j] + brg[1];
        float g2 = acc[2][j] + brg[2];
        float g3 = acc[3][j] + brg[3];
        if (ISL1) {
            g0 = fmaf(w1x[0], xt, g0);
            g1 = fmaf(w1x[1], xt, g1);
            g2 = fmaf(w1x[2], xt, g2);
            g3 = fmaf(w1x[3], xt, g3);
        }
        float ig = sigf(g0), fg = sigf(g1), gg = tanh_f(g2), og = sigf(g3);
        float cn = fmaf(fg, cpriv, ig * gg);
        cpriv = cn;
        float h = og * tanh_f(cn);
        union { _Float16 hf; unsigned short us; } cv;
        cv.hf = (_Float16)h;
        // plain 2B store: L1 is write-through; __syncthreads drains vmcnt before
        // the flag post, so this is globally visible when the flag says so.
        brow[(size_t)j * 512 + HBASE + m * RG + rg] = cv.us;
    }
}

__global__ __launch_bounds__(512)
void lstm_v2(const float* __restrict__ inp,
             const float* __restrict__ w1ih, const float* __restrict__ w1hh,
             const float* __restrict__ b1ih, const float* __restrict__ b1hh,
             const float* __restrict__ w2ih, const float* __restrict__ w2hh,
             const float* __restrict__ b2ih, const float* __restrict__ b2hh,
             const float* __restrict__ w3ih, const float* __restrict__ w3hh,
             const float* __restrict__ b3ih, const float* __restrict__ b3hh,
             const float* __restrict__ w4ih, const float* __restrict__ w4hh,
             const float* __restrict__ b4ih, const float* __restrict__ b4hh,
             const float* __restrict__ w5ih, const float* __restrict__ w5hh,
             const float* __restrict__ b5ih, const float* __restrict__ b5hh,
             const float* __restrict__ wlin, const float* __restrict__ blin,
             float* __restrict__ out, char* __restrict__ wsb)
{
    extern __shared__ __align__(16) _Float16 smem[];
    const int tid  = threadIdx.x;
    const int lane = tid & 63;
    const int wave = tid >> 6;
    const int g = blockIdx.x & 31;     // group (members share mod-8 class -> same XCD)
    const int m = blockIdx.x >> 5;     // member 0..7
    _Float16* Xp = smem + wave * XPW;  // this wave's private x buffer

    unsigned short* board = (unsigned short*)wsb;
    int* flags = (int*)(wsb + FLAGS_BOFF);

    // ---- register-resident state (loaded once; statically indexed throughout) ----
    half8v wfrag[24];                  // max live: L2 = 4 gates * J=6
    float brg[4]  = {0.f, 0.f, 0.f, 0.f};
    float w1x[4]  = {0.f, 0.f, 0.f, 0.f};
    float wl[16];
    float bl = 0.f;
    float cpriv = 0.f;

    if (wave < 4) {                    // L1: RG=32 KG=8 J=4, k = h1(256)
        const int kg = tid & 7, rg = tid >> 3;
#pragma unroll
        for (int i = 0; i < 4; ++i) {
            const int grow = i * 256 + m * 32 + rg;
#pragma unroll
            for (int jj = 0; jj < 4; ++jj) {
                const int k0 = kg * 8 + jj * 64;
                half8v w;
#pragma unroll
                for (int e = 0; e < 8; ++e)
                    w[e] = (_Float16)w1hh[grow * 256 + k0 + e];
                wfrag[i * 4 + jj] = w;
            }
            brg[i] = b1ih[grow] + b1hh[grow];
            w1x[i] = w1ih[grow];
        }
    } else if (wave < 6) {             // L2: RG=16 KG=8 J=6, k = h1(256)|h2(128)
        const int u = tid - 256;
        const int kg = u & 7, rg = u >> 3;
#pragma unroll
        for (int i = 0; i < 4; ++i) {
            const int grow = i * 128 + m * 16 + rg;
#pragma unroll
            for (int jj = 0; jj < 6; ++jj) {
                const int k0 = kg * 8 + jj * 64;
                half8v w;
#pragma unroll
                for (int e = 0; e < 8; ++e) {
                    const int k = k0 + e;
                    float v = (k < 256) ? w2ih[grow * 256 + k]
                                        : w2hh[grow * 128 + (k - 256)];
                    w[e] = (_Float16)v;
                }
                wfrag[i * 6 + jj] = w;
            }
            brg[i] = b2ih[grow] + b2hh[grow];
        }
    } else if (wave == 6) {            // L3: RG=8 KG=8 J=3, k = h2(128)|h3(64)
        const int u = tid - 384;
        const int kg = u & 7, rg = u >> 3;
#pragma unroll
        for (int i = 0; i < 4; ++i) {
            const int grow = i * 64 + m * 8 + rg;
#pragma unroll
            for (int jj = 0; jj < 3; ++jj) {
                const int k0 = kg * 8 + jj * 64;
                half8v w;
#pragma unroll
                for (int e = 0; e < 8; ++e) {
                    const int k = k0 + e;
                    float v = (k < 128) ? w3ih[grow * 128 + k]
                                        : w3hh[grow * 64 + (k - 128)];
                    w[e] = (_Float16)v;
                }
                wfrag[i * 3 + jj] = w;
            }
            brg[i] = b3ih[grow] + b3hh[grow];
        }
    } else {                           // wave 7: L4 (16 lanes) + L5 (8) + out (4)
        const int u = tid - 448;
        if (u < 16) {                  // L4: RG=4 KG=4 J=3, k = h3(64)|h4(32)
            const int kg = u & 3, rg = u >> 2;
#pragma unroll
            for (int i = 0; i < 4; ++i) {
                const int grow = i * 32 + m * 4 + rg;
#pragma unroll
                for (int jj = 0; jj < 3; ++jj) {
                    const int k0 = kg * 8 + jj * 32;
                    half8v w;
#pragma unroll
                    for (int e = 0; e < 8; ++e) {
                        const int k = k0 + e;
                        float v = (k < 64) ? w4ih[grow * 64 + k]
                                           : w4hh[grow * 32 + (k - 64)];
                        w[e] = (_Float16)v;
                    }
                    wfrag[i * 3 + jj] = w;
                }
                brg[i] = b4ih[grow] + b4hh[grow];
            }
        } else if (u < 24) {           // L5: RG=2 KG=4 J=2, k = h4(32)|h5(16)|pad
            const int uu = u - 16, kg = uu & 3, rg = uu >> 2;
#pragma unroll
            for (int i = 0; i < 4; ++i) {
                const int grow = i * 16 + m * 2 + rg;
#pragma unroll
                for (int jj = 0; jj < 2; ++jj) {
                    const int k0 = kg * 8 + jj * 32;
                    half8v w;
#pragma unroll
                    for (int e = 0; e < 8; ++e) {
                        const int k = k0 + e;
                        float v = (k < 32) ? w5ih[grow * 32 + k]
                                : (k < 48 ? w5hh[grow * 16 + (k - 32)] : 0.f);
                        w[e] = (_Float16)v;
                    }
                    wfrag[i * 2 + jj] = w;
                }
                brg[i] = b5ih[grow] + b5hh[grow];
            }
        } else if (u < 28) {           // out head
#pragma unroll
            for (int j = 0; j < 16; ++j) wl[j] = wlin[j];
            bl = blin[0];
        }
    }

    const int* fp = flags + (g * 8 + (lane & 7)) * 16;

    for (int s = 0; s < NSTEP; ++s) {
        const int pr = (s + 1) & 1, pw = s & 1;
        const unsigned short* bsrc = board + (size_t)((pr * 32 + g) * 4) * 512;
        unsigned short* brow       = board + (size_t)((pw * 32 + g) * 4) * 512;

        // ---- per-wave poll: all 8 member flags >= s (trivially true at s=0).
        // flag >= s  =>  that member passed its step-(s-1) barrier  =>  its board
        // writes are drained AND its step-(s-1) reads of slot[(s+1)&1] are done,
        // so it is safe to read slot[pr] and overwrite slot[pw].
        while (true) {
            int f = __hip_atomic_load(fp, __ATOMIC_RELAXED, __HIP_MEMORY_SCOPE_AGENT);
            if (__all(f >= s)) break;
        }

        if (wave < 4) {
            if (s < 2048) {
                float xt = inp[(size_t)(g * 4 + (lane & 3)) * TT + s];
                stage_x<4, 0>(bsrc, Xp, lane);          // h1: k 0..256
                layer_v2<32, 8, 4, 0, 0, true, true>(
                    wfrag, brg, w1x, xt, Xp, brow, cpriv, tid, m);
            }
        } else if (wave < 6) {
            if (s >= 1 && s <= 2048) {
                stage_x<6, 0>(bsrc, Xp, lane);          // h1|h2: k 0..384
                layer_v2<16, 8, 6, 0, 256, false, true>(
                    wfrag, brg, w1x, 0.f, Xp, brow, cpriv, tid - 256, m);
            }
        } else if (wave == 6) {
            if (s >= 2 && s <= 2049) {
                stage_x<3, 256>(bsrc, Xp, lane);        // h2|h3: k 256..448
                layer_v2<8, 8, 3, 0, 384, false, true>(
                    wfrag, brg, w1x, 0.f, Xp, brow, cpriv, tid - 384, m);
            }
        } else {
            const int u = tid - 448;
            if (s >= 3 && s <= 2052)
                stage_x<2, 384>(bsrc, Xp, lane);        // h3|h4|h5|pad: k 384..512
            if (u < 16) {
                if (s >= 3 && s <= 2050)
                    layer_v2<4, 4, 3, 0, 448, false, false>(
                        wfrag, brg, w1x, 0.f, Xp, brow, cpriv, u, m);
            } else if (u < 24) {
                if (s >= 4 && s <= 2051)
                    layer_v2<2, 4, 2, 64, 480, false, false>(
                        wfrag, brg, w1x, 0.f, Xp, brow, cpriv, u - 16, m);
            } else if (u < 28) {
                if (m == 0 && s >= 5) {
                    const int b = u - 24;
                    float a = bl;
#pragma unroll
                    for (int j = 0; j < 16; ++j)
                        a = fmaf((float)Xp[b * XW + 96 + j], wl[j], a);
                    out[(size_t)(g * 4 + b) * TT + (s - 5)] = a;
                }
            }
        }

        // ---- single barrier per step: drains vmcnt(0) for every wave, so all
        // board stores are globally visible before the flag store issues.
        __syncthreads();
        if (tid == 0)
            __hip_atomic_store(flags + (g * 8 + m) * 16, s + 1,
                               __ATOMIC_RELAXED, __HIP_MEMORY_SCOPE_AGENT);
    }
}

extern "C" void kernel_launch(void* const* d_in, const int* in_sizes, int n_in,
                              void* d_out, int out_size, void* d_ws, size_t ws_size,
                              hipStream_t stream) {
    const float* p[23];
    for (int i = 0; i < 23 && i < n_in; ++i) p[i] = (const float*)d_in[i];

    (void)hipFuncSetAttribute((const void*)lstm_v2,
                              hipFuncAttributeMaxDynamicSharedMemorySize,
                              LDS_BYTES);

    prep_zero<<<dim3((ZERO_F4 + 255) / 256), dim3(256), 0, stream>>>((float4*)d_ws);

    // grid 256 = CU count; >80KB dynamic LDS forces 1 block/CU -> all
    // 32 groups x 8 members co-resident (required for the flag protocol).
    lstm_v2<<<dim3(256), dim3(512), LDS_BYTES, stream>>>(
        p[0],
        p[1],  p[2],  p[3],  p[4],
        p[5],  p[6],  p[7],  p[8],
        p[9],  p[10], p[11], p[12],
        p[13], p[14], p[15], p[16],
        p[17], p[18], p[19], p[20],
        p[21], p[22],
        (float*)d_out, (char*)d_ws);
}